// Round 10
// baseline (57.692 us; speedup 1.0000x reference)
//
#include <hip/hip_runtime.h>

typedef unsigned short ushort_t;
typedef unsigned int uint_t;

constexpr int BSZ = 32;
constexpr int CH  = 64;
constexpr int HW  = 32 * 128;   // 4096
constexpr int NP  = 512;
constexpr float EPS = 1e-8f;
constexpr float SCL = 2.8853900817779268f;   // 2*log2(e): pre-scale W,QB -> tanh needs no mul
constexpr float L2E = 1.4426950408889634f;   // log2(e)

using short8 = __attribute__((ext_vector_type(8))) short;   // 8 bf16 (4 VGPRs)
using f32x4  = __attribute__((ext_vector_type(4))) float;

__device__ __forceinline__ ushort_t f2bf(float f) {   // fp32 -> bf16 RNE
    uint_t u = __builtin_bit_cast(uint_t, f);
    u += 0x7FFFu + ((u >> 16) & 1u);
    return (ushort_t)(u >> 16);
}
__device__ __forceinline__ float bf2f(ushort_t b) {
    uint_t u = ((uint_t)b) << 16;
    return __builtin_bit_cast(float, u);
}

// async global->LDS, 16B/lane (LDS dest = wave-uniform base + lane*16)
__device__ __forceinline__ void gld16(const void* g, void* l) {
    __builtin_amdgcn_global_load_lds(
        (const __attribute__((address_space(1))) void*)g,
        (__attribute__((address_space(3))) void*)l, 16, 0, 0);
}

// K0: W' = SCL*Ua_w split to bf16 hi/lo in MFMA-frag order
//   fidx = r*8192 + mt*1024 + ks*512 + (kg*16+lm)*8 + j
// QB = SCL*(query+Ua_b); Va2 = -2*Va_w; SUMVW = sum(Va_w).
__global__ __launch_bounds__(256) void k_prep(
    const float* __restrict__ Ua_w, const float* __restrict__ Ua_b,
    const float* __restrict__ query, const float* __restrict__ Va_w,
    ushort_t* __restrict__ Whi_f, ushort_t* __restrict__ Wlo_f,
    float* __restrict__ QB, float* __restrict__ Va2, float* __restrict__ SUMVW)
{
    const int i = blockIdx.x * 256 + threadIdx.x;
    if (i < NP * CH) {
        const int o = i >> 6, ch = i & 63;
        const int r = o >> 7, mt = (o >> 4) & 7, lm = o & 15;
        const int ks = ch >> 5, kg = (ch >> 3) & 3, j = ch & 7;
        const int fidx = r * 8192 + mt * 1024 + ks * 512 + (kg * 16 + lm) * 8 + j;
        float x = Ua_w[i] * SCL;
        ushort_t h = f2bf(x);
        Whi_f[fidx] = h;
        Wlo_f[fidx] = f2bf(x - bf2f(h));
    }
    if (i < BSZ * NP) {
        QB[i] = SCL * (query[i] + Ua_b[i & (NP - 1)]);
    }
    if (i < NP) {
        Va2[i] = -2.0f * Va_w[i];
    }
    if (blockIdx.x == 0 && threadIdx.x < 64) {
        float s = 0.0f;
#pragma unroll
        for (int t = 0; t < 8; ++t) s += Va_w[threadIdx.x + t * 64];
#pragma unroll
        for (int off = 32; off > 0; off >>= 1) s += __shfl_down(s, off, 64);
        if (threadIdx.x == 0) SUMVW[0] = s;
    }
}

// K1: full logit + exp per position.
// Wave owns 64 positions (nt=4). 512 blocks = exactly 2/CU; (256,2) -> 256
// VGPR cap, ~180 used, no spill. Per r: stage 32KB W chunk, then 8 m-tiles
// with a 2-state pipeline: MFMA(mt) issue -> prefetch(mt+1) -> tanh-epilogue
// of mt-1 runs under the matrix pipe (round-9 showed lockstep phases
// serialize the MFMA/VALU/LDS pipes: 22%+41%+35% summing to ~100%).
// Epilogue algebra: sum vw*tanh = SUMVW + sum (-2vw)*rcp(exp2(s)+1)
// -> 2 VALU + 2 trans per element; qb rides the MFMA C-operand.
__global__ __launch_bounds__(256, 2) void k_scores(
    const float* __restrict__ key,
    const ushort_t* __restrict__ Whi_f, const ushort_t* __restrict__ Wlo_f,
    const float* __restrict__ QB, const float* __restrict__ Va2,
    const float* __restrict__ SUMVW, const float* __restrict__ Va_b,
    float* __restrict__ e_exp)
{
    const int bx = blockIdx.x;            // 0..511
    const int b  = bx >> 4;               // batch
    const int pc = bx & 15;               // 256-pos chunk
    const int wv = threadIdx.x >> 6;
    const int l  = threadIdx.x & 63;
    const int lm = l & 15;                // col-in-tile (A row / B,C col)
    const int kg = l >> 4;                // k-group
    const int p0 = pc * 256 + wv * 64;    // wave's first position

    __shared__ ushort_t Wl[16384];        // [hi 8K | lo 8K] ushorts, frag order
    __shared__ float qbl[NP];
    __shared__ float va2l[NP];

    if (wv == 0) {
        gld16(QB + b * NP + l * 4,       &qbl[0]);
        gld16(QB + b * NP + 256 + l * 4, &qbl[256]);
    }
    if (wv == 1) {
        gld16(Va2 + l * 4,       &va2l[0]);
        gld16(Va2 + 256 + l * 4, &va2l[256]);
    }

    // ---- load + bf16-split this wave's key ONCE: B = key[b,:,p0..p0+63] ----
    short8 Bh[4][2], Bl8[4][2];
    const float* kb = key + (size_t)b * CH * HW;
#pragma unroll
    for (int nt = 0; nt < 4; ++nt) {
#pragma unroll
        for (int ks = 0; ks < 2; ++ks) {
#pragma unroll
            for (int j = 0; j < 8; ++j) {
                float x = kb[(size_t)(ks * 32 + kg * 8 + j) * HW + (p0 + nt * 16 + lm)];
                ushort_t h = f2bf(x);
                Bh[nt][ks][j]  = (short)h;
                Bl8[nt][ks][j] = (short)f2bf(x - bf2f(h));
            }
        }
    }

    float P[4] = {0.0f, 0.0f, 0.0f, 0.0f};   // per-nt partial of (-2vw)*rcp

    for (int r = 0; r < 4; ++r) {
        // stage W chunk r: 32KB across 4 waves (8 gld16 each)
#pragma unroll
        for (int t = 0; t < 4; ++t) {
            const int c = wv * 4 + t;
            gld16(Whi_f + (size_t)r * 8192 + c * 512 + l * 8, &Wl[c * 512]);
            gld16(Wlo_f + (size_t)r * 8192 + c * 512 + l * 8, &Wl[8192 + c * 512]);
        }
        __syncthreads();                  // staging visible

        // 2-state m-tile pipeline (full unroll -> all-static)
        f32x4 accE[4], accO[4];
        short8 cA0 = *(const short8*)&Wl[l * 8];
        short8 cA1 = *(const short8*)&Wl[512 + l * 8];
        short8 cA2 = *(const short8*)&Wl[8192 + l * 8];
        short8 cA3 = *(const short8*)&Wl[8192 + 512 + l * 8];
        f32x4 cqb  = *(const f32x4*)&qbl[r * 128 + kg * 4];
        f32x4 cva2 = *(const f32x4*)&va2l[r * 128 + kg * 4];
        f32x4 pva2 = cva2;

#pragma unroll
        for (int mt = 0; mt < 8; ++mt) {
            f32x4* acc  = (mt & 1) ? accO : accE;
            f32x4* pacc = (mt & 1) ? accE : accO;

            // 4 independent chains of depth 6, round-robin issue; C-init = qb
#pragma unroll
            for (int nt = 0; nt < 4; ++nt)
                acc[nt] = __builtin_amdgcn_mfma_f32_16x16x32_bf16(cA0, Bh[nt][0], cqb, 0, 0, 0);
#pragma unroll
            for (int nt = 0; nt < 4; ++nt)
                acc[nt] = __builtin_amdgcn_mfma_f32_16x16x32_bf16(cA1, Bh[nt][1], acc[nt], 0, 0, 0);
#pragma unroll
            for (int nt = 0; nt < 4; ++nt)
                acc[nt] = __builtin_amdgcn_mfma_f32_16x16x32_bf16(cA0, Bl8[nt][0], acc[nt], 0, 0, 0);
#pragma unroll
            for (int nt = 0; nt < 4; ++nt)
                acc[nt] = __builtin_amdgcn_mfma_f32_16x16x32_bf16(cA1, Bl8[nt][1], acc[nt], 0, 0, 0);
#pragma unroll
            for (int nt = 0; nt < 4; ++nt)
                acc[nt] = __builtin_amdgcn_mfma_f32_16x16x32_bf16(cA2, Bh[nt][0], acc[nt], 0, 0, 0);
#pragma unroll
            for (int nt = 0; nt < 4; ++nt)
                acc[nt] = __builtin_amdgcn_mfma_f32_16x16x32_bf16(cA3, Bh[nt][1], acc[nt], 0, 0, 0);

            // prefetch mt+1 operands (independent of the MFMAs above)
            short8 nA0, nA1, nA2, nA3; f32x4 nqb, nva2;
            if (mt < 7) {
                nA0 = *(const short8*)&Wl[(mt + 1) * 1024 + l * 8];
                nA1 = *(const short8*)&Wl[(mt + 1) * 1024 + 512 + l * 8];
                nA2 = *(const short8*)&Wl[8192 + (mt + 1) * 1024 + l * 8];
                nA3 = *(const short8*)&Wl[8192 + (mt + 1) * 1024 + 512 + l * 8];
                nqb  = *(const f32x4*)&qbl[r * 128 + (mt + 1) * 16 + kg * 4];
                nva2 = *(const f32x4*)&va2l[r * 128 + (mt + 1) * 16 + kg * 4];
            }

            // epilogue of PREVIOUS m-tile: runs under the matrix pipe
            if (mt > 0) {
#pragma unroll
                for (int nt = 0; nt < 4; ++nt)
#pragma unroll
                    for (int rr = 0; rr < 4; ++rr) {
                        float e  = __builtin_amdgcn_exp2f(pacc[nt][rr]);
                        float rc = __builtin_amdgcn_rcpf(e + 1.0f);
                        P[nt] = fmaf(pva2[rr], rc, P[nt]);
                    }
            }
            pva2 = cva2;
            if (mt < 7) {
                cA0 = nA0; cA1 = nA1; cA2 = nA2; cA3 = nA3;
                cqb = nqb; cva2 = nva2;
            }
        }
        // drain: epilogue of mt=7 (lives in accO)
#pragma unroll
        for (int nt = 0; nt < 4; ++nt)
#pragma unroll
            for (int rr = 0; rr < 4; ++rr) {
                float e  = __builtin_amdgcn_exp2f(accO[nt][rr]);
                float rc = __builtin_amdgcn_rcpf(e + 1.0f);
                P[nt] = fmaf(pva2[rr], rc, P[nt]);
            }
        __syncthreads();                  // reads done before restage
    }

    // reduce over the 4 k-groups; add SUMVW once
#pragma unroll
    for (int nt = 0; nt < 4; ++nt) {
        P[nt] += __shfl_xor(P[nt], 16, 64);
        P[nt] += __shfl_xor(P[nt], 32, 64);
    }
    const float base = SUMVW[0] + Va_b[0];
    if (kg == 0) {
#pragma unroll
        for (int nt = 0; nt < 4; ++nt)
            e_exp[(size_t)b * HW + p0 + nt * 16 + lm] =
                __builtin_amdgcn_exp2f((P[nt] + base) * L2E);
    }
}

// K2: per-batch denominator
__global__ __launch_bounds__(256) void k_denom(
    const float* __restrict__ e_exp,
    float* __restrict__ inv_denom)
{
    const int b = blockIdx.x;
    const int tid = threadIdx.x;
    const float4* e4 = (const float4*)(e_exp + (size_t)b * HW);
    float s = 0.0f;
#pragma unroll
    for (int i = 0; i < HW / 4 / 256; ++i) {
        float4 v = e4[tid + i * 256];
        s += (v.x + v.y) + (v.z + v.w);
    }
#pragma unroll
    for (int off = 32; off > 0; off >>= 1) s += __shfl_down(s, off, 64);
    __shared__ float wsum[4];
    if ((tid & 63) == 0) wsum[tid >> 6] = s;
    __syncthreads();
    if (tid == 0) {
        float t = (wsum[0] + wsum[1]) + (wsum[2] + wsum[3]);
        inv_denom[b] = 1.0f / (t + EPS);
    }
}

// K3: out[b,c,p] = feature[b,c,p] * e_exp[b,p] * inv_denom[b]  (float4)
__global__ __launch_bounds__(256) void k_scale(
    const float* __restrict__ feature,
    const float* __restrict__ e_exp,
    const float* __restrict__ inv_denom,
    float* __restrict__ out)
{
    const int idx = blockIdx.x * 256 + threadIdx.x;   // float4 index
    const int pq = idx & (HW / 4 - 1);
    const int bc = idx >> 10;
    const int b  = bc >> 6;

    const float sc = inv_denom[b];
    const float4 e = ((const float4*)(e_exp + (size_t)b * HW))[pq];
    const float4 f = ((const float4*)feature)[idx];
    float4 o;
    o.x = f.x * (e.x * sc);
    o.y = f.y * (e.y * sc);
    o.z = f.z * (e.z * sc);
    o.w = f.w * (e.w * sc);
    ((float4*)out)[idx] = o;
}

extern "C" void kernel_launch(void* const* d_in, const int* in_sizes, int n_in,
                              void* d_out, int out_size, void* d_ws, size_t ws_size,
                              hipStream_t stream)
{
    const float* feature = (const float*)d_in[0];
    const float* query   = (const float*)d_in[1];
    const float* key     = (const float*)d_in[2];
    const float* Ua_w    = (const float*)d_in[3];
    const float* Ua_b    = (const float*)d_in[4];
    const float* Va_w    = (const float*)d_in[5];
    const float* Va_b    = (const float*)d_in[6];

    // workspace layout
    ushort_t* Whi_f = (ushort_t*)d_ws;                      // 512*64 frag-order
    ushort_t* Wlo_f = Whi_f + NP * CH;                      // 512*64
    float* QB        = (float*)(Wlo_f + NP * CH);           // 32*512
    float* Va2       = QB + BSZ * NP;                       // 512
    float* SUMVW     = Va2 + NP;                            // 1 (+pad)
    float* e_exp     = SUMVW + 4;                           // 32*4096
    float* inv_denom = e_exp + BSZ * HW;                    // 32

    k_prep<<<(NP * CH) / 256, 256, 0, stream>>>(
        Ua_w, Ua_b, query, Va_w, Whi_f, Wlo_f, QB, Va2, SUMVW);
    k_scores<<<BSZ * (HW / 256), 256, 0, stream>>>(
        key, Whi_f, Wlo_f, QB, Va2, SUMVW, Va_b, e_exp);
    k_denom<<<BSZ, 256, 0, stream>>>(e_exp, inv_denom);
    k_scale<<<(BSZ * CH * HW / 4) / 256, 256, 0, stream>>>(
        feature, e_exp, inv_denom, (float*)d_out);
}

// Round 11
// 54.413 us; speedup vs baseline: 1.0602x; 1.0602x over previous
//
#include <hip/hip_runtime.h>

typedef unsigned short ushort_t;
typedef unsigned int uint_t;

constexpr int BSZ = 32;
constexpr int CH  = 64;
constexpr int HW  = 32 * 128;   // 4096
constexpr int NP  = 512;
constexpr float EPS = 1e-8f;
constexpr float SCL = 2.8853900817779268f;   // 2*log2(e): pre-scale W,QB -> tanh needs no mul
constexpr float L2E = 1.4426950408889634f;   // log2(e)

using short8 = __attribute__((ext_vector_type(8))) short;   // 8 bf16 (4 VGPRs)
using f32x4  = __attribute__((ext_vector_type(4))) float;

__device__ __forceinline__ ushort_t f2bf(float f) {   // fp32 -> bf16 RNE
    uint_t u = __builtin_bit_cast(uint_t, f);
    u += 0x7FFFu + ((u >> 16) & 1u);
    return (ushort_t)(u >> 16);
}
__device__ __forceinline__ float bf2f(ushort_t b) {
    uint_t u = ((uint_t)b) << 16;
    return __builtin_bit_cast(float, u);
}

// async global->LDS, 16B/lane (LDS dest = wave-uniform base + lane*16)
__device__ __forceinline__ void gld16(const void* g, void* l) {
    __builtin_amdgcn_global_load_lds(
        (const __attribute__((address_space(1))) void*)g,
        (__attribute__((address_space(3))) void*)l, 16, 0, 0);
}

// K0: W' = SCL*Ua_w split to bf16 hi/lo in MFMA-frag order
//   fidx = mt*1024 + ks*512 + (kg*16+lm)*8 + j   (mt = o>>4 = 0..31)
// QB = SCL*(query+Ua_b); Va2 = -2*Va_w; SUMVW = sum(Va_w).
__global__ __launch_bounds__(256) void k_prep(
    const float* __restrict__ Ua_w, const float* __restrict__ Ua_b,
    const float* __restrict__ query, const float* __restrict__ Va_w,
    ushort_t* __restrict__ Whi_f, ushort_t* __restrict__ Wlo_f,
    float* __restrict__ QB, float* __restrict__ Va2, float* __restrict__ SUMVW)
{
    const int i = blockIdx.x * 256 + threadIdx.x;
    if (i < NP * CH) {
        const int o = i >> 6, ch = i & 63;
        const int mt = o >> 4, lm = o & 15;
        const int ks = ch >> 5, kg = (ch >> 3) & 3, j = ch & 7;
        const int fidx = mt * 1024 + ks * 512 + (kg * 16 + lm) * 8 + j;
        float x = Ua_w[i] * SCL;
        ushort_t h = f2bf(x);
        Whi_f[fidx] = h;
        Wlo_f[fidx] = f2bf(x - bf2f(h));
    }
    if (i < BSZ * NP) {
        QB[i] = SCL * (query[i] + Ua_b[i & (NP - 1)]);
    }
    if (i < NP) {
        Va2[i] = -2.0f * Va_w[i];
    }
    if (blockIdx.x == 0 && threadIdx.x < 64) {
        float s = 0.0f;
#pragma unroll
        for (int t = 0; t < 8; ++t) s += Va_w[threadIdx.x + t * 64];
#pragma unroll
        for (int off = 32; off > 0; off >>= 1) s += __shfl_down(s, off, 64);
        if (threadIdx.x == 0) SUMVW[0] = s;
    }
}

// K1: full logit + exp per position, plus per-(b,pc) partial denominator.
// LDS cut to 20.3KB (occupancy experiment: r9's 36.9KB measured only ~2.2
// blocks/CU resident). W streamed in SIXTEEN 8KB chunks (2 m-tiles each),
// double-buffered: stage c+1 (4 gld16/wave... 2/wave) overlaps compute of c,
// one barrier per chunk. nt=2 + split hi/lo accumulators = 4 independent
// depth-3 MFMA chains at ~100 VGPR (the only shape that never spilled).
// Epilogue: sum vw*tanh = SUMVW + sum (-2vw)*rcp(exp2(s)+1); qb rides the
// MFMA C-operand of the accA chain.
__global__ __launch_bounds__(256, 4) void k_scores(
    const float* __restrict__ key,
    const ushort_t* __restrict__ Whi_f, const ushort_t* __restrict__ Wlo_f,
    const float* __restrict__ QB, const float* __restrict__ Va2,
    const float* __restrict__ SUMVW, const float* __restrict__ Va_b,
    float* __restrict__ e_exp, float* __restrict__ dsum)
{
    const int bx = blockIdx.x;            // 0..1023
    const int b  = bx >> 5;               // batch
    const int pc = bx & 31;               // 128-pos chunk
    const int wv = threadIdx.x >> 6;
    const int l  = threadIdx.x & 63;
    const int lm = l & 15;                // col-in-tile (A row / B,C col)
    const int kg = l >> 4;                // k-group
    const int p0 = pc * 128 + wv * 32;    // wave's first position

    __shared__ ushort_t Wb[2][4096];      // dbuf: [hi mt0|hi mt1|lo mt0|lo mt1] x1024
    __shared__ float qbl[NP];
    __shared__ float vwl[NP];
    __shared__ float bsum[4];

    // stage qb/vw once (drained by the prologue barrier)
    if (wv == 0) {
        gld16(QB + b * NP + l * 4,       &qbl[0]);
        gld16(QB + b * NP + 256 + l * 4, &qbl[256]);
    }
    if (wv == 1) {
        gld16(Va2 + l * 4,       &vwl[0]);
        gld16(Va2 + 256 + l * 4, &vwl[256]);
    }

    // wave-specific W staging source: wv0/1 -> hi mt{0,1}, wv2/3 -> lo mt{0,1}
    const ushort_t* wsrc = (wv < 2) ? Whi_f : Wlo_f;
    const int wsub = (wv & 1) * 1024;     // which mt of the chunk

    // prologue: stage chunk 0 into buf 0
    gld16(wsrc + wsub + l * 8,       &Wb[0][wv * 1024]);
    gld16(wsrc + wsub + 512 + l * 8, &Wb[0][wv * 1024 + 512]);

    // ---- load + bf16-split this wave's key ONCE: B = key[b,:,p0..p0+31] ----
    short8 Bh[2][2], Bl8[2][2];
    const float* kb = key + (size_t)b * CH * HW;
#pragma unroll
    for (int nt = 0; nt < 2; ++nt) {
#pragma unroll
        for (int ks = 0; ks < 2; ++ks) {
#pragma unroll
            for (int j = 0; j < 8; ++j) {
                float x = kb[(size_t)(ks * 32 + kg * 8 + j) * HW + (p0 + nt * 16 + lm)];
                ushort_t h = f2bf(x);
                Bh[nt][ks][j]  = (short)h;
                Bl8[nt][ks][j] = (short)f2bf(x - bf2f(h));
            }
        }
    }

    __syncthreads();                      // chunk 0 + qb/vw staged

    float P[2] = {0.0f, 0.0f};            // per-nt partial of (-2vw)*rcp

    for (int c = 0; c < 16; ++c) {
        const int buf = c & 1;
        // stage chunk c+1 into the other buffer (lands under this compute)
        if (c + 1 < 16) {
            const ushort_t* s = wsrc + (c + 1) * 2048 + wsub;
            gld16(s + l * 8,       &Wb[buf ^ 1][wv * 1024]);
            gld16(s + 512 + l * 8, &Wb[buf ^ 1][wv * 1024 + 512]);
        }

#pragma unroll
        for (int m01 = 0; m01 < 2; ++m01) {
            const int mt = c * 2 + m01;   // global m-tile 0..31
            const short8 Ah0 = *(const short8*)&Wb[buf][m01 * 1024 + l * 8];
            const short8 Ah1 = *(const short8*)&Wb[buf][m01 * 1024 + 512 + l * 8];
            const short8 Al0 = *(const short8*)&Wb[buf][2048 + m01 * 1024 + l * 8];
            const short8 Al1 = *(const short8*)&Wb[buf][2048 + m01 * 1024 + 512 + l * 8];
            const f32x4 qb = *(const f32x4*)&qbl[mt * 16 + kg * 4];
            const f32x4 vw = *(const f32x4*)&vwl[mt * 16 + kg * 4];

            // 4 independent chains of depth 3; accA C-init = qb
            f32x4 accA[2], accB[2];
#pragma unroll
            for (int nt = 0; nt < 2; ++nt) {
                accA[nt] = __builtin_amdgcn_mfma_f32_16x16x32_bf16(Ah0, Bh[nt][0], qb, 0, 0, 0);
                accB[nt] = __builtin_amdgcn_mfma_f32_16x16x32_bf16(Ah1, Bh[nt][1],
                               (f32x4){0.f, 0.f, 0.f, 0.f}, 0, 0, 0);
            }
#pragma unroll
            for (int nt = 0; nt < 2; ++nt) {
                accA[nt] = __builtin_amdgcn_mfma_f32_16x16x32_bf16(Ah0, Bl8[nt][0], accA[nt], 0, 0, 0);
                accB[nt] = __builtin_amdgcn_mfma_f32_16x16x32_bf16(Ah1, Bl8[nt][1], accB[nt], 0, 0, 0);
            }
#pragma unroll
            for (int nt = 0; nt < 2; ++nt) {
                accA[nt] = __builtin_amdgcn_mfma_f32_16x16x32_bf16(Al0, Bh[nt][0], accA[nt], 0, 0, 0);
                accB[nt] = __builtin_amdgcn_mfma_f32_16x16x32_bf16(Al1, Bh[nt][1], accB[nt], 0, 0, 0);
            }

            // epilogue: s pre-scaled by 2*log2(e); P += (-2vw)*rcp(exp2(s)+1)
#pragma unroll
            for (int nt = 0; nt < 2; ++nt)
#pragma unroll
                for (int rr = 0; rr < 4; ++rr) {
                    float s  = accA[nt][rr] + accB[nt][rr];
                    float e  = __builtin_amdgcn_exp2f(s);
                    float rc = __builtin_amdgcn_rcpf(e + 1.0f);
                    P[nt] = fmaf(vw[rr], rc, P[nt]);
                }
        }
        __syncthreads();                  // reads done; next stage drained
    }

    // reduce over the 4 k-groups; every lane of kg==0 gets its positions
#pragma unroll
    for (int nt = 0; nt < 2; ++nt) {
        P[nt] += __shfl_xor(P[nt], 16, 64);
        P[nt] += __shfl_xor(P[nt], 32, 64);
    }
    const float base = SUMVW[0] + Va_b[0];
    float ee = 0.0f;
    if (kg == 0) {
        float e0 = __builtin_amdgcn_exp2f((P[0] + base) * L2E);
        float e1 = __builtin_amdgcn_exp2f((P[1] + base) * L2E);
        e_exp[(size_t)b * HW + p0 + lm]      = e0;
        e_exp[(size_t)b * HW + p0 + 16 + lm] = e1;
        ee = e0 + e1;
    }
    // block partial denominator (deterministic; no atomics)
#pragma unroll
    for (int off = 1; off < 64; off <<= 1) ee += __shfl_xor(ee, off, 64);
    if (l == 0) bsum[wv] = ee;
    __syncthreads();
    if (threadIdx.x == 0)
        dsum[b * 32 + pc] = (bsum[0] + bsum[1]) + (bsum[2] + bsum[3]);
}

// K2: out[b,c,p] = feature[b,c,p] * e_exp[b,p] / (sum dsum[b,:] + EPS)
__global__ __launch_bounds__(256) void k_scale(
    const float* __restrict__ feature,
    const float* __restrict__ e_exp,
    const float* __restrict__ dsum,
    float* __restrict__ out)
{
    const int idx = blockIdx.x * 256 + threadIdx.x;   // float4 index
    const int pq = idx & (HW / 4 - 1);
    const int bc = idx >> 10;
    const int b  = bc >> 6;                            // block-uniform

    float dsm = EPS;
#pragma unroll
    for (int i = 0; i < 32; ++i) dsm += dsum[b * 32 + i];   // uniform s_loads
    const float sc = 1.0f / dsm;

    const float4 e = ((const float4*)(e_exp + (size_t)b * HW))[pq];
    const float4 f = ((const float4*)feature)[idx];
    float4 o;
    o.x = f.x * (e.x * sc);
    o.y = f.y * (e.y * sc);
    o.z = f.z * (e.z * sc);
    o.w = f.w * (e.w * sc);
    ((float4*)out)[idx] = o;
}

extern "C" void kernel_launch(void* const* d_in, const int* in_sizes, int n_in,
                              void* d_out, int out_size, void* d_ws, size_t ws_size,
                              hipStream_t stream)
{
    const float* feature = (const float*)d_in[0];
    const float* query   = (const float*)d_in[1];
    const float* key     = (const float*)d_in[2];
    const float* Ua_w    = (const float*)d_in[3];
    const float* Ua_b    = (const float*)d_in[4];
    const float* Va_w    = (const float*)d_in[5];
    const float* Va_b    = (const float*)d_in[6];

    // workspace layout
    ushort_t* Whi_f = (ushort_t*)d_ws;                      // 512*64 frag-order
    ushort_t* Wlo_f = Whi_f + NP * CH;                      // 512*64
    float* QB        = (float*)(Wlo_f + NP * CH);           // 32*512
    float* Va2       = QB + BSZ * NP;                       // 512
    float* SUMVW     = Va2 + NP;                            // 1 (+pad)
    float* e_exp     = SUMVW + 4;                           // 32*4096
    float* dsum      = e_exp + BSZ * HW;                    // 32*32

    k_prep<<<(NP * CH) / 256, 256, 0, stream>>>(
        Ua_w, Ua_b, query, Va_w, Whi_f, Wlo_f, QB, Va2, SUMVW);
    k_scores<<<BSZ * (HW / 128), 256, 0, stream>>>(
        key, Whi_f, Wlo_f, QB, Va2, SUMVW, Va_b, e_exp, dsum);
    k_scale<<<(BSZ * CH * HW / 4) / 256, 256, 0, stream>>>(
        feature, e_exp, dsum, (float*)d_out);
}

// Round 12
// 53.085 us; speedup vs baseline: 1.0868x; 1.0250x over previous
//
#include <hip/hip_runtime.h>

typedef unsigned short ushort_t;
typedef unsigned int uint_t;

constexpr int BSZ = 32;
constexpr int CH  = 64;
constexpr int HW  = 32 * 128;   // 4096
constexpr int NP  = 512;
constexpr int OSPLIT = 2;             // o-split across blocks
constexpr int OCHUNK = NP / OSPLIT;   // 256 o per block = 8 chunks of 2 m-tiles
constexpr float EPS = 1e-8f;
constexpr float SCL = 2.8853900817779268f;   // 2*log2(e): pre-scale W,QB -> tanh needs no mul
constexpr float L2E = 1.4426950408889634f;   // log2(e)

using short8 = __attribute__((ext_vector_type(8))) short;   // 8 bf16 (4 VGPRs)
using f32x4  = __attribute__((ext_vector_type(4))) float;

__device__ __forceinline__ ushort_t f2bf(float f) {   // fp32 -> bf16 RNE
    uint_t u = __builtin_bit_cast(uint_t, f);
    u += 0x7FFFu + ((u >> 16) & 1u);
    return (ushort_t)(u >> 16);
}
__device__ __forceinline__ float bf2f(ushort_t b) {
    uint_t u = ((uint_t)b) << 16;
    return __builtin_bit_cast(float, u);
}

// async global->LDS, 16B/lane (LDS dest = wave-uniform base + lane*16)
__device__ __forceinline__ void gld16(const void* g, void* l) {
    __builtin_amdgcn_global_load_lds(
        (const __attribute__((address_space(1))) void*)g,
        (__attribute__((address_space(3))) void*)l, 16, 0, 0);
}

// K0: W' = SCL*Ua_w split to bf16 hi/lo in MFMA-frag order
//   fidx = mt*1024 + ks*512 + (kg*16+lm)*8 + j   (mt = o>>4 = 0..31)
// QB = SCL*(query+Ua_b); Va2 = -2*Va_w; SUMVW = sum(Va_w).
__global__ __launch_bounds__(256) void k_prep(
    const float* __restrict__ Ua_w, const float* __restrict__ Ua_b,
    const float* __restrict__ query, const float* __restrict__ Va_w,
    ushort_t* __restrict__ Whi_f, ushort_t* __restrict__ Wlo_f,
    float* __restrict__ QB, float* __restrict__ Va2, float* __restrict__ SUMVW)
{
    const int i = blockIdx.x * 256 + threadIdx.x;
    if (i < NP * CH) {
        const int o = i >> 6, ch = i & 63;
        const int mt = o >> 4, lm = o & 15;
        const int ks = ch >> 5, kg = (ch >> 3) & 3, j = ch & 7;
        const int fidx = mt * 1024 + ks * 512 + (kg * 16 + lm) * 8 + j;
        float x = Ua_w[i] * SCL;
        ushort_t h = f2bf(x);
        Whi_f[fidx] = h;
        Wlo_f[fidx] = f2bf(x - bf2f(h));
    }
    if (i < BSZ * NP) {
        QB[i] = SCL * (query[i] + Ua_b[i & (NP - 1)]);
    }
    if (i < NP) {
        Va2[i] = -2.0f * Va_w[i];
    }
    if (blockIdx.x == 0 && threadIdx.x < 64) {
        float s = 0.0f;
#pragma unroll
        for (int t = 0; t < 8; ++t) s += Va_w[threadIdx.x + t * 64];
#pragma unroll
        for (int off = 32; off > 0; off >>= 1) s += __shfl_down(s, off, 64);
        if (threadIdx.x == 0) SUMVW[0] = s;
    }
}

// K1: partial tanh-sums over an o-half.
// Round-11 falsified the LDS-pool theory: occupancy pinned at ~30% because
// the GRID was 4 blocks/CU = 16 waves/CU max. Fix: o-split x2 -> 2048 blocks
// = 8 blocks/CU = 32 waves/CU (8 waves/SIMD at VGPR<=64, LDS 18.3KB x 8 =
// 146KB <= 160KB). Wave shape unchanged from r11 (nt=2, split hi/lo accs =
// 4 independent depth-3 chains, 52 VGPR, never spilled).
// Epilogue: P = sum (-2vw)*rcp(exp2(s)+1) over the half; k_denom finishes.
__global__ __launch_bounds__(256, 4) void k_scores(
    const float* __restrict__ key,
    const ushort_t* __restrict__ Whi_f, const ushort_t* __restrict__ Wlo_f,
    const float* __restrict__ QB, const float* __restrict__ Va2,
    float* __restrict__ e_part)
{
    const int bx = blockIdx.x;            // 0..2047
    const int r  = bx >> 10;              // o-half
    const int b  = (bx >> 5) & 31;        // batch
    const int pc = bx & 31;               // 128-pos chunk
    const int wv = threadIdx.x >> 6;
    const int l  = threadIdx.x & 63;
    const int lm = l & 15;                // col-in-tile (A row / B,C col)
    const int kg = l >> 4;                // k-group
    const int p0 = pc * 128 + wv * 32;    // wave's first position

    __shared__ ushort_t Wb[2][4096];      // dbuf chunk: [hi mt0|hi mt1|lo mt0|lo mt1]
    __shared__ float qbl[OCHUNK];
    __shared__ float vwl[OCHUNK];

    // stage qb/vw for this o-half (one gld16 each; drained by prologue barrier)
    if (wv == 0) gld16(QB + b * NP + r * OCHUNK + l * 4, &qbl[0]);
    if (wv == 1) gld16(Va2 + r * OCHUNK + l * 4, &vwl[0]);

    // wave-specific W staging: wv0/1 -> hi mt{0,1}, wv2/3 -> lo mt{0,1}
    const ushort_t* wsrc = (wv < 2) ? Whi_f : Wlo_f;
    const int wsub = (wv & 1) * 1024;

    // prologue: stage chunk 0 of this half into buf 0
    {
        const ushort_t* s = wsrc + (size_t)r * 8 * 2048 + wsub;
        gld16(s + l * 8,       &Wb[0][wv * 1024]);
        gld16(s + 512 + l * 8, &Wb[0][wv * 1024 + 512]);
    }

    // ---- load + bf16-split this wave's key ONCE: B = key[b,:,p0..p0+31] ----
    short8 Bh[2][2], Bl8[2][2];
    const float* kb = key + (size_t)b * CH * HW;
#pragma unroll
    for (int nt = 0; nt < 2; ++nt) {
#pragma unroll
        for (int ks = 0; ks < 2; ++ks) {
#pragma unroll
            for (int j = 0; j < 8; ++j) {
                float x = kb[(size_t)(ks * 32 + kg * 8 + j) * HW + (p0 + nt * 16 + lm)];
                ushort_t h = f2bf(x);
                Bh[nt][ks][j]  = (short)h;
                Bl8[nt][ks][j] = (short)f2bf(x - bf2f(h));
            }
        }
    }

    __syncthreads();                      // chunk 0 + qb/vw staged

    float P[2] = {0.0f, 0.0f};            // per-nt partial of (-2vw)*rcp

    for (int c = 0; c < 8; ++c) {
        const int buf = c & 1;
        // stage chunk c+1 into the other buffer (lands under this compute)
        if (c + 1 < 8) {
            const ushort_t* s = wsrc + ((size_t)r * 8 + c + 1) * 2048 + wsub;
            gld16(s + l * 8,       &Wb[buf ^ 1][wv * 1024]);
            gld16(s + 512 + l * 8, &Wb[buf ^ 1][wv * 1024 + 512]);
        }

#pragma unroll
        for (int m01 = 0; m01 < 2; ++m01) {
            const int mt = c * 2 + m01;   // local m-tile 0..15
            const short8 Ah0 = *(const short8*)&Wb[buf][m01 * 1024 + l * 8];
            const short8 Ah1 = *(const short8*)&Wb[buf][m01 * 1024 + 512 + l * 8];
            const short8 Al0 = *(const short8*)&Wb[buf][2048 + m01 * 1024 + l * 8];
            const short8 Al1 = *(const short8*)&Wb[buf][2048 + m01 * 1024 + 512 + l * 8];
            const f32x4 qb = *(const f32x4*)&qbl[mt * 16 + kg * 4];
            const f32x4 vw = *(const f32x4*)&vwl[mt * 16 + kg * 4];

            // 4 independent chains of depth 3; accA C-init = qb
            f32x4 accA[2], accB[2];
#pragma unroll
            for (int nt = 0; nt < 2; ++nt) {
                accA[nt] = __builtin_amdgcn_mfma_f32_16x16x32_bf16(Ah0, Bh[nt][0], qb, 0, 0, 0);
                accB[nt] = __builtin_amdgcn_mfma_f32_16x16x32_bf16(Ah1, Bh[nt][1],
                               (f32x4){0.f, 0.f, 0.f, 0.f}, 0, 0, 0);
            }
#pragma unroll
            for (int nt = 0; nt < 2; ++nt) {
                accA[nt] = __builtin_amdgcn_mfma_f32_16x16x32_bf16(Ah0, Bl8[nt][0], accA[nt], 0, 0, 0);
                accB[nt] = __builtin_amdgcn_mfma_f32_16x16x32_bf16(Ah1, Bl8[nt][1], accB[nt], 0, 0, 0);
            }
#pragma unroll
            for (int nt = 0; nt < 2; ++nt) {
                accA[nt] = __builtin_amdgcn_mfma_f32_16x16x32_bf16(Al0, Bh[nt][0], accA[nt], 0, 0, 0);
                accB[nt] = __builtin_amdgcn_mfma_f32_16x16x32_bf16(Al1, Bh[nt][1], accB[nt], 0, 0, 0);
            }

            // epilogue: s pre-scaled by 2*log2(e); P += (-2vw)*rcp(exp2(s)+1)
#pragma unroll
            for (int nt = 0; nt < 2; ++nt)
#pragma unroll
                for (int rr = 0; rr < 4; ++rr) {
                    float s  = accA[nt][rr] + accB[nt][rr];
                    float e  = __builtin_amdgcn_exp2f(s);
                    float rc = __builtin_amdgcn_rcpf(e + 1.0f);
                    P[nt] = fmaf(vw[rr], rc, P[nt]);
                }
        }
        __syncthreads();                  // reads done; next stage drained
    }

    // reduce over the 4 k-groups; kg==0 lanes hold the half-sums
#pragma unroll
    for (int nt = 0; nt < 2; ++nt) {
        P[nt] += __shfl_xor(P[nt], 16, 64);
        P[nt] += __shfl_xor(P[nt], 32, 64);
    }
    if (kg == 0) {
        e_part[(size_t)r * (BSZ * HW) + (size_t)b * HW + p0 + lm]      = P[0];
        e_part[(size_t)r * (BSZ * HW) + (size_t)b * HW + p0 + 16 + lm] = P[1];
    }
}

// K2: combine o-halves, exp, per-batch denominator.
__global__ __launch_bounds__(256) void k_denom(
    const float* __restrict__ e_part,
    const float* __restrict__ SUMVW, const float* __restrict__ Va_b,
    float* __restrict__ e_exp, float* __restrict__ inv_denom)
{
    const int b = blockIdx.x;
    const int tid = threadIdx.x;
    const float base = SUMVW[0] + Va_b[0];
    float s = 0.0f;
#pragma unroll
    for (int i = 0; i < HW / 256; ++i) {
        const int idx = b * HW + i * 256 + tid;
        float p = e_part[idx] + e_part[BSZ * HW + idx];
        float e = __builtin_amdgcn_exp2f((p + base) * L2E);
        e_exp[idx] = e;
        s += e;
    }
#pragma unroll
    for (int off = 32; off > 0; off >>= 1) s += __shfl_down(s, off, 64);
    __shared__ float wsum[4];
    if ((tid & 63) == 0) wsum[tid >> 6] = s;
    __syncthreads();
    if (tid == 0) {
        float t = (wsum[0] + wsum[1]) + (wsum[2] + wsum[3]);
        inv_denom[b] = 1.0f / (t + EPS);
    }
}

// K3: out[b,c,p] = feature[b,c,p] * e_exp[b,p] * inv_denom[b]  (float4)
__global__ __launch_bounds__(256) void k_scale(
    const float* __restrict__ feature,
    const float* __restrict__ e_exp,
    const float* __restrict__ inv_denom,
    float* __restrict__ out)
{
    const int idx = blockIdx.x * 256 + threadIdx.x;   // float4 index
    const int pq = idx & (HW / 4 - 1);
    const int bc = idx >> 10;
    const int b  = bc >> 6;

    const float sc = inv_denom[b];
    const float4 e = ((const float4*)(e_exp + (size_t)b * HW))[pq];
    const float4 f = ((const float4*)feature)[idx];
    float4 o;
    o.x = f.x * (e.x * sc);
    o.y = f.y * (e.y * sc);
    o.z = f.z * (e.z * sc);
    o.w = f.w * (e.w * sc);
    ((float4*)out)[idx] = o;
}

extern "C" void kernel_launch(void* const* d_in, const int* in_sizes, int n_in,
                              void* d_out, int out_size, void* d_ws, size_t ws_size,
                              hipStream_t stream)
{
    const float* feature = (const float*)d_in[0];
    const float* query   = (const float*)d_in[1];
    const float* key     = (const float*)d_in[2];
    const float* Ua_w    = (const float*)d_in[3];
    const float* Ua_b    = (const float*)d_in[4];
    const float* Va_w    = (const float*)d_in[5];
    const float* Va_b    = (const float*)d_in[6];

    // workspace layout
    ushort_t* Whi_f = (ushort_t*)d_ws;                      // 512*64 frag-order
    ushort_t* Wlo_f = Whi_f + NP * CH;                      // 512*64
    float* QB        = (float*)(Wlo_f + NP * CH);           // 32*512
    float* Va2       = QB + BSZ * NP;                       // 512
    float* SUMVW     = Va2 + NP;                            // 1 (+pad)
    float* e_part    = SUMVW + 4;                           // 2*32*4096
    float* e_exp     = e_part + (size_t)OSPLIT * BSZ * HW;  // 32*4096
    float* inv_denom = e_exp + BSZ * HW;                    // 32

    k_prep<<<(NP * CH) / 256, 256, 0, stream>>>(
        Ua_w, Ua_b, query, Va_w, Whi_f, Wlo_f, QB, Va2, SUMVW);
    k_scores<<<BSZ * (HW / 128) * OSPLIT, 256, 0, stream>>>(
        key, Whi_f, Wlo_f, QB, Va2, e_part);
    k_denom<<<BSZ, 256, 0, stream>>>(e_part, SUMVW, Va_b, e_exp, inv_denom);
    k_scale<<<(BSZ * CH * HW / 4) / 256, 256, 0, stream>>>(
        feature, e_exp, inv_denom, (float*)d_out);
}